// Round 5
// baseline (52.103 us; speedup 1.0000x reference)
//
#include <hip/hip_runtime.h>
#include <hip/hip_bf16.h>

// Problem constants (from reference)
#define BATCH    1048576
#define TPW      16               // tiles per wave; 4096 waves x 16 = 65536 tiles
#define K_SCALE  4.32808512266689f   // 3.0 * log2(e): fold scale into exp2 domain
#define K_CLAMP  14.4269504088896f   // 10.0 * log2(e)

typedef __attribute__((ext_vector_type(8))) short  bf16x8;  // 8 bf16 = 4 VGPRs
typedef __attribute__((ext_vector_type(4))) float  f32x4;   // MFMA accumulator

__device__ __forceinline__ short f2bf(float f) {
    __hip_bfloat16 h = __float2bfloat16(f);   // RNE v_cvt
    return __builtin_bit_cast(short, h);
}

// D = W @ x^T (m=hid, n=batch, k=in), bf16 MFMA.
// C/D layout: col = lane&15 = batch, row = 4*(lane>>4)+i = hid -> LSE over hid
// is 15 VALU adds + 2 shfl_xor. 2-deep load pipeline: at iter i issue loads
// for tile i+2, stage (vmcnt-wait) loads for tile i+1, compute tile i.
// Grid 1024 x 256 @ 4 blocks/CU: every block resident from t=0 (single
// dispatch generation), 64 KB contiguous HBM stream per wave.
__global__ __launch_bounds__(256, 4)
void fused_lse_mish(const float* __restrict__ x,
                    const float* __restrict__ W,
                    float* __restrict__ out) {
    // wave-private double-buffered bf16 staging (16 x 64 = 2KB per buffer)
    __shared__ alignas(16) unsigned char lds[4 * 2 * 2048];

    const int tid  = threadIdx.x;
    const int wid  = tid >> 6;
    const int lane = tid & 63;
    const int l15  = lane & 15;   // 0..15
    const int l4   = lane >> 4;   // 0..3
    unsigned char* wlds = lds + wid * 4096;

    // ---- A operand = W (m=hid, k=in), register-resident.
    // A-frag(t,s): lane holds A[m=16t+l15][k=32s+8*l4+e] (W row-contiguous)
    bf16x8 wfrag[4][2];
    #pragma unroll
    for (int t = 0; t < 4; ++t) {
        const float* wp = W + (t * 16 + l15) * 64 + l4 * 8;
        #pragma unroll
        for (int s = 0; s < 2; ++s) {
            float4 w0 = *reinterpret_cast<const float4*>(wp + s * 32);
            float4 w1 = *reinterpret_cast<const float4*>(wp + s * 32 + 4);
            bf16x8 f;
            f[0] = f2bf(w0.x); f[1] = f2bf(w0.y); f[2] = f2bf(w0.z); f[3] = f2bf(w0.w);
            f[4] = f2bf(w1.x); f[5] = f2bf(w1.y); f[6] = f2bf(w1.z); f[7] = f2bf(w1.w);
            wfrag[t][s] = f;
        }
    }

    // B-frag read addrs (B[k][n]=x[n][k]: row = l15, k-bytes l4*16 (+64)),
    // swizzled: phys = row*128 + (colbyte ^ ((row&7)<<4))
    const unsigned rswz = (unsigned)((l15 & 7) << 4);
    const unsigned ra0  = (unsigned)(l15 * 128) + (((unsigned)(l4 * 16))      ^ rswz);
    const unsigned ra1  = (unsigned)(l15 * 128) + (((unsigned)(64 + l4 * 16)) ^ rswz);

    const int gwave = (int)((blockIdx.x * blockDim.x + tid) >> 6);
    const float* xp = x + (size_t)gwave * (TPW * 1024) + l4 * 64 + l15 * 4;
    float* op = out + gwave * (TPW * 16);

    // loads for one tile: 4x dwordx4, each 1KB dense across the wave
#define LOADSET(dst, ti)                                                  \
    {                                                                     \
        const float* q_ = xp + (ti) * 1024;                               \
        dst[0] = *reinterpret_cast<const float4*>(q_);                    \
        dst[1] = *reinterpret_cast<const float4*>(q_ + 256);              \
        dst[2] = *reinterpret_cast<const float4*>(q_ + 512);              \
        dst[3] = *reinterpret_cast<const float4*>(q_ + 768);              \
    }

#define STAGE(src, buf)                                                   \
    {                                                                     \
        unsigned char* nb_ = (buf);                                       \
        _Pragma("unroll")                                                 \
        for (int it = 0; it < 4; ++it) {                                  \
            const int r_ = it * 4 + l4;                                   \
            float4 v_ = src[it];                                          \
            short4 b_;                                                    \
            b_.x = f2bf(v_.x); b_.y = f2bf(v_.y);                         \
            b_.z = f2bf(v_.z); b_.w = f2bf(v_.w);                         \
            unsigned wa_ = (unsigned)(r_ * 128) +                         \
                (((unsigned)(l15 * 8)) ^ ((unsigned)((r_ & 7) << 4)));    \
            *reinterpret_cast<short4*>(nb_ + wa_) = b_;                   \
        }                                                                 \
    }

    // pend[t&1] holds the in-flight loads for tile t (t = i+1, i+2)
    float4 pend[2][4];
    float4 t0[4];
    LOADSET(t0, 0);
    LOADSET(pend[1], 1);
    STAGE(t0, wlds);              // waits only tile0's loads (older)

    #pragma unroll 2
    for (int i = 0; i < TPW; ++i) {
        // issue loads for tile i+2 (newest; ~2 compute-phases of latency cover)
        if (i + 2 < TPW) LOADSET(pend[i & 1], i + 2);

        // ---- compute tile i
        unsigned char* cur = wlds + ((i & 1) ? 2048 : 0);
        bf16x8 b0 = *reinterpret_cast<const bf16x8*>(cur + ra0);  // k 0..31
        bf16x8 b1 = *reinterpret_cast<const bf16x8*>(cur + ra1);  // k 32..63

        f32x4 acc[4];
        #pragma unroll
        for (int t = 0; t < 4; ++t) {
            f32x4 z; z[0] = 0.f; z[1] = 0.f; z[2] = 0.f; z[3] = 0.f;
            z = __builtin_amdgcn_mfma_f32_16x16x32_bf16(wfrag[t][0], b0, z, 0, 0, 0);
            z = __builtin_amdgcn_mfma_f32_16x16x32_bf16(wfrag[t][1], b1, z, 0, 0, 0);
            acc[t] = z;
        }

        // epilogue: lane holds 16 hid-values of batch col l15.
        // exp(clamp(3z,±10)) == exp2(clamp(z*3*log2e, ±10*log2e))
        float sum = 0.f;
        #pragma unroll
        for (int t = 0; t < 4; ++t) {
            #pragma unroll
            for (int r = 0; r < 4; ++r) {
                float v = acc[t][r] * K_SCALE;
                v = fminf(fmaxf(v, -K_CLAMP), K_CLAMP);
                sum += __builtin_amdgcn_exp2f(v);      // bare v_exp_f32
            }
        }
        sum += __shfl_xor(sum, 16);
        sum += __shfl_xor(sum, 32);

        float lse = __logf(sum);
        float sp  = __logf(1.f + __expf(lse));          // softplus(lse)
        float e2  = __expf(2.f * sp);
        float th  = 1.f - 2.f / (e2 + 1.f);             // tanh(sp)
        float res = lse * th;

        // ---- stage tile i+1 (vmcnt-waits only the OLDER pending set;
        // issued a full iteration ago -> long latency cover)
        if (i + 1 < TPW) {
            unsigned char* nxt = wlds + (((i + 1) & 1) ? 2048 : 0);
            STAGE(pend[(i + 1) & 1], nxt);
        }

        if (lane < 16) op[i * 16 + l15] = res;
    }
#undef LOADSET
#undef STAGE
}

extern "C" void kernel_launch(void* const* d_in, const int* in_sizes, int n_in,
                              void* d_out, int out_size, void* d_ws, size_t ws_size,
                              hipStream_t stream) {
    const float* x = (const float*)d_in[0];   // [BATCH, 64] fp32
    const float* W = (const float*)d_in[1];   // [64, 64]   fp32
    float* out = (float*)d_out;               // [BATCH] fp32 (B x 1)

    dim3 grid(1024), block(256);              // 4096 waves x 16 tiles, 1 generation
    hipLaunchKernelGGL(fused_lse_mish, grid, block, 0, stream, x, W, out);
}

// Round 6
// 46.316 us; speedup vs baseline: 1.1250x; 1.1250x over previous
//
#include <hip/hip_runtime.h>
#include <hip/hip_bf16.h>

// Problem constants (from reference)
#define BATCH    1048576
#define TPW      8                // tiles per wave; 8192 waves x 8 = 65536 tiles
#define K_SCALE  4.32808512266689f   // 3.0 * log2(e): fold scale into exp2 domain
#define K_CLAMP  14.4269504088896f   // 10.0 * log2(e)

typedef __attribute__((ext_vector_type(8))) short  bf16x8;  // 8 bf16 = 4 VGPRs
typedef __attribute__((ext_vector_type(4))) float  f32x4;   // MFMA accumulator

__device__ __forceinline__ short f2bf(float f) {
    __hip_bfloat16 h = __float2bfloat16(f);   // RNE v_cvt
    return __builtin_bit_cast(short, h);
}

// D = W @ x^T (m=hid, n=batch, k=in), bf16 MFMA.
// C/D layout: col = lane&15 = batch, row = 4*(lane>>4)+i = hid -> LSE over hid
// is 15 VALU adds + 2 shfl_xor. 2-deep load pipeline: at iter i issue loads
// for tile i+2, stage (vmcnt-wait) loads for tile i+1, compute tile i.
// Grid 2048 x 256: two dispatch generations -> dynamic CU load balancing
// (R5 showed single-generation 1024x16 regresses 10%).
__global__ __launch_bounds__(256, 4)
void fused_lse_mish(const float* __restrict__ x,
                    const float* __restrict__ W,
                    float* __restrict__ out) {
    // wave-private double-buffered bf16 staging (16 x 64 = 2KB per buffer)
    __shared__ alignas(16) unsigned char lds[4 * 2 * 2048];

    const int tid  = threadIdx.x;
    const int wid  = tid >> 6;
    const int lane = tid & 63;
    const int l15  = lane & 15;   // 0..15
    const int l4   = lane >> 4;   // 0..3
    unsigned char* wlds = lds + wid * 4096;

    // ---- A operand = W (m=hid, k=in), register-resident.
    // A-frag(t,s): lane holds A[m=16t+l15][k=32s+8*l4+e] (W row-contiguous)
    bf16x8 wfrag[4][2];
    #pragma unroll
    for (int t = 0; t < 4; ++t) {
        const float* wp = W + (t * 16 + l15) * 64 + l4 * 8;
        #pragma unroll
        for (int s = 0; s < 2; ++s) {
            float4 w0 = *reinterpret_cast<const float4*>(wp + s * 32);
            float4 w1 = *reinterpret_cast<const float4*>(wp + s * 32 + 4);
            bf16x8 f;
            f[0] = f2bf(w0.x); f[1] = f2bf(w0.y); f[2] = f2bf(w0.z); f[3] = f2bf(w0.w);
            f[4] = f2bf(w1.x); f[5] = f2bf(w1.y); f[6] = f2bf(w1.z); f[7] = f2bf(w1.w);
            wfrag[t][s] = f;
        }
    }

    // B-frag read addrs (B[k][n]=x[n][k]: row = l15, k-bytes l4*16 (+64)),
    // swizzled: phys = row*128 + (colbyte ^ ((row&7)<<4))
    const unsigned rswz = (unsigned)((l15 & 7) << 4);
    const unsigned ra0  = (unsigned)(l15 * 128) + (((unsigned)(l4 * 16))      ^ rswz);
    const unsigned ra1  = (unsigned)(l15 * 128) + (((unsigned)(64 + l4 * 16)) ^ rswz);

    const int gwave = (int)((blockIdx.x * blockDim.x + tid) >> 6);
    const float* xp = x + (size_t)gwave * (TPW * 1024) + l4 * 64 + l15 * 4;
    float* op = out + gwave * (TPW * 16);

    // loads for one tile: 4x dwordx4, each 1KB dense across the wave
#define LOADSET(dst, ti)                                                  \
    {                                                                     \
        const float* q_ = xp + (ti) * 1024;                               \
        dst[0] = *reinterpret_cast<const float4*>(q_);                    \
        dst[1] = *reinterpret_cast<const float4*>(q_ + 256);              \
        dst[2] = *reinterpret_cast<const float4*>(q_ + 512);              \
        dst[3] = *reinterpret_cast<const float4*>(q_ + 768);              \
    }

#define STAGE(src, buf)                                                   \
    {                                                                     \
        unsigned char* nb_ = (buf);                                       \
        _Pragma("unroll")                                                 \
        for (int it = 0; it < 4; ++it) {                                  \
            const int r_ = it * 4 + l4;                                   \
            float4 v_ = src[it];                                          \
            short4 b_;                                                    \
            b_.x = f2bf(v_.x); b_.y = f2bf(v_.y);                         \
            b_.z = f2bf(v_.z); b_.w = f2bf(v_.w);                         \
            unsigned wa_ = (unsigned)(r_ * 128) +                         \
                (((unsigned)(l15 * 8)) ^ ((unsigned)((r_ & 7) << 4)));    \
            *reinterpret_cast<short4*>(nb_ + wa_) = b_;                   \
        }                                                                 \
    }

    // pend[t&1] holds the in-flight loads for tile t (t = i+1, i+2)
    float4 pend[2][4];
    float4 t0[4];
    LOADSET(t0, 0);
    LOADSET(pend[1], 1);
    STAGE(t0, wlds);              // waits only tile0's loads (older)

    #pragma unroll
    for (int i = 0; i < TPW; ++i) {
        // issue loads for tile i+2 (newest; ~2 compute-phases of latency cover)
        if (i + 2 < TPW) LOADSET(pend[i & 1], i + 2);

        // ---- compute tile i
        unsigned char* cur = wlds + ((i & 1) ? 2048 : 0);
        bf16x8 b0 = *reinterpret_cast<const bf16x8*>(cur + ra0);  // k 0..31
        bf16x8 b1 = *reinterpret_cast<const bf16x8*>(cur + ra1);  // k 32..63

        f32x4 acc[4];
        #pragma unroll
        for (int t = 0; t < 4; ++t) {
            f32x4 z; z[0] = 0.f; z[1] = 0.f; z[2] = 0.f; z[3] = 0.f;
            z = __builtin_amdgcn_mfma_f32_16x16x32_bf16(wfrag[t][0], b0, z, 0, 0, 0);
            z = __builtin_amdgcn_mfma_f32_16x16x32_bf16(wfrag[t][1], b1, z, 0, 0, 0);
            acc[t] = z;
        }

        // epilogue: lane holds 16 hid-values of batch col l15.
        // exp(clamp(3z,±10)) == exp2(clamp(z*3*log2e, ±10*log2e))
        float sum = 0.f;
        #pragma unroll
        for (int t = 0; t < 4; ++t) {
            #pragma unroll
            for (int r = 0; r < 4; ++r) {
                float v = acc[t][r] * K_SCALE;
                v = fminf(fmaxf(v, -K_CLAMP), K_CLAMP);
                sum += __builtin_amdgcn_exp2f(v);      // bare v_exp_f32
            }
        }
        sum += __shfl_xor(sum, 16);
        sum += __shfl_xor(sum, 32);

        float lse = __logf(sum);
        float sp  = __logf(1.f + __expf(lse));          // softplus(lse)
        float e2  = __expf(2.f * sp);
        float th  = 1.f - 2.f / (e2 + 1.f);             // tanh(sp)
        float res = lse * th;

        // ---- stage tile i+1 (vmcnt-waits only the OLDER pending set;
        // issued a full iteration ago -> long latency cover)
        if (i + 1 < TPW) {
            unsigned char* nxt = wlds + (((i + 1) & 1) ? 2048 : 0);
            STAGE(pend[(i + 1) & 1], nxt);
        }

        if (lane < 16) op[i * 16 + l15] = res;
    }
#undef LOADSET
#undef STAGE
}

extern "C" void kernel_launch(void* const* d_in, const int* in_sizes, int n_in,
                              void* d_out, int out_size, void* d_ws, size_t ws_size,
                              hipStream_t stream) {
    const float* x = (const float*)d_in[0];   // [BATCH, 64] fp32
    const float* W = (const float*)d_in[1];   // [64, 64]   fp32
    float* out = (float*)d_out;               // [BATCH] fp32 (B x 1)

    dim3 grid(2048), block(256);              // 8192 waves x 8 tiles, 2 generations
    hipLaunchKernelGGL(fused_lse_mish, grid, block, 0, stream, x, W, out);
}